// Round 1
// baseline (814.936 us; speedup 1.0000x reference)
//
#include <hip/hip_runtime.h>

#define NB 1024
#define N1P 116
#define N2P 200
#define NN1 (NB * N1P)      // 118784
#define NN2 (NB * N2P)      // 204800
#define HD 32

// ---------------------------------------------------------------------------
// GEMM: out[N,32] = X[N,K] @ W[K,32].  Block tile: 128 rows x 32 cols.
// 256 threads, each computes 4 rows (stride 32) x 4 cols.  K chunked by 32,
// zero-padded tails.  LDS: sX[128][36] (padded, conflict-free b128), sW[32][32].
// ---------------------------------------------------------------------------
template <int K>
__global__ __launch_bounds__(256) void gemm32(const float* __restrict__ X,
                                              const float* __restrict__ W,
                                              float* __restrict__ out) {
    constexpr int KC = 32;
    constexpr int SX = KC + 4;  // 36-float row stride: 4*36 % 32 = 16.. rows stride 36 -> bank offset 4/row
    __shared__ float sX[128 * SX];
    __shared__ float sW[KC * 32];

    const int tid = threadIdx.x;
    const long row0 = (long)blockIdx.x * 128;

    const int hg = tid & 7;          // 8 h-groups of 4
    const int rg = tid >> 3;         // 32 row-groups; rows rg + 32*i
    const int h0 = hg * 4;

    const int lj = tid & 31;         // loader: col 0..31
    const int lr = tid >> 5;         // loader: row 0..7 (+8 per pass)

    float acc[4][4];
#pragma unroll
    for (int i = 0; i < 4; ++i)
#pragma unroll
        for (int c = 0; c < 4; ++c) acc[i][c] = 0.f;

    for (int kc0 = 0; kc0 < K; kc0 += KC) {
        // stage x chunk: 128 rows x 32 k (zero-padded past K)
        {
            const int k = kc0 + lj;
            const bool ok = (k < K);
#pragma unroll
            for (int p = 0; p < 16; ++p) {
                const int r = lr + 8 * p;
                sX[r * SX + lj] = ok ? X[(row0 + r) * (long)K + k] : 0.f;
            }
        }
        // stage W chunk: 32 k x 32 h
#pragma unroll
        for (int p = 0; p < 4; ++p) {
            const int idx = tid + 256 * p;
            const int kk = idx >> 5, jj = idx & 31;
            const int k = kc0 + kk;
            sW[kk * 32 + jj] = (k < K) ? W[(long)k * 32 + jj] : 0.f;
        }
        __syncthreads();

#pragma unroll
        for (int j2 = 0; j2 < KC; j2 += 4) {
            float4 wv0 = *(const float4*)&sW[(j2 + 0) * 32 + h0];
            float4 wv1 = *(const float4*)&sW[(j2 + 1) * 32 + h0];
            float4 wv2 = *(const float4*)&sW[(j2 + 2) * 32 + h0];
            float4 wv3 = *(const float4*)&sW[(j2 + 3) * 32 + h0];
#pragma unroll
            for (int i = 0; i < 4; ++i) {
                float4 xv = *(const float4*)&sX[(rg + 32 * i) * SX + j2];
                acc[i][0] += xv.x * wv0.x + xv.y * wv1.x + xv.z * wv2.x + xv.w * wv3.x;
                acc[i][1] += xv.x * wv0.y + xv.y * wv1.y + xv.z * wv2.y + xv.w * wv3.y;
                acc[i][2] += xv.x * wv0.z + xv.y * wv1.z + xv.z * wv2.z + xv.w * wv3.z;
                acc[i][3] += xv.x * wv0.w + xv.y * wv1.w + xv.z * wv2.w + xv.w * wv3.w;
            }
        }
        __syncthreads();
    }

#pragma unroll
    for (int i = 0; i < 4; ++i) {
        const long r = row0 + rg + 32 * i;
        float4 o;
        o.x = acc[i][0]; o.y = acc[i][1]; o.z = acc[i][2]; o.w = acc[i][3];
        *(float4*)&out[r * 32 + h0] = o;
    }
}

// ---------------------------------------------------------------------------
// Aggregation: out[i,h] = relu(b[h] + sum_{k<16} vals[i*16+k]*sup[cols[i*16+k],h])
// rows are contiguous (node i owns edges [i*16, i*16+16)).  8 nodes/block.
// ---------------------------------------------------------------------------
__global__ __launch_bounds__(256) void agg_relu(const int* __restrict__ cols,
                                                const float* __restrict__ vals,
                                                const float* __restrict__ sup,
                                                const float* __restrict__ bias,
                                                float* __restrict__ out) {
    const int tid = threadIdx.x;
    const int h = tid & 31;
    const long i = (long)blockIdx.x * 8 + (tid >> 5);
    const long e0 = i * 16;
    float acc = bias[h];
#pragma unroll
    for (int k = 0; k < 16; ++k) {
        const int c = cols[e0 + k];
        const float v = vals[e0 + k];
        acc += v * sup[(long)c * 32 + h];
    }
    out[i * 32 + h] = fmaxf(acc, 0.f);
}

// ---------------------------------------------------------------------------
// Per-graph mean+max pool over nodes.  grid = B, block = 256 (32 h x 8 slices)
// feats layout per graph: [mean_b1(32) max_b1(32) mean_b2(32) max_b2(32)]
// ---------------------------------------------------------------------------
template <int NPER>
__global__ __launch_bounds__(256) void pool_meanmax(const float* __restrict__ hin,
                                                    float* __restrict__ feats,
                                                    int foff) {
    const int g = blockIdx.x;
    const int tid = threadIdx.x;
    const int h = tid & 31, s = tid >> 5;
    const float* base = hin + (long)g * NPER * 32;
    float sum = 0.f, mx = -1e30f;
    for (int n = s; n < NPER; n += 8) {
        const float v = base[n * 32 + h];
        sum += v;
        mx = fmaxf(mx, v);
    }
    __shared__ float sS[256], sM[256];
    sS[tid] = sum;
    sM[tid] = mx;
    __syncthreads();
    if (tid < 32) {
#pragma unroll
        for (int q = 1; q < 8; ++q) {
            sum += sS[tid + 32 * q];
            mx = fmaxf(mx, sM[tid + 32 * q]);
        }
        feats[(long)g * 128 + foff + h] = sum * (1.0f / NPER);
        feats[(long)g * 128 + foff + 32 + h] = mx;
    }
}

// ---------------------------------------------------------------------------
// MLP head: [B,128] -> relu(fc1) -> relu(fc2) -> fc3 -> [B,2]
// 8 graphs per block (32 lanes each).
// ---------------------------------------------------------------------------
__global__ __launch_bounds__(256) void mlp_head(const float* __restrict__ feats,
                                                const float* __restrict__ W1,
                                                const float* __restrict__ b1,
                                                const float* __restrict__ W2,
                                                const float* __restrict__ b2,
                                                const float* __restrict__ W3,
                                                const float* __restrict__ b3,
                                                float* __restrict__ out) {
    __shared__ float sW1[128 * 32];
    __shared__ float sW2[32 * 16];
    __shared__ float sW3[16 * 2];
    __shared__ float sB1[32], sB2[16], sB3[2];
    __shared__ float sF[8 * 128];
    __shared__ float sH1[8 * 32];
    __shared__ float sH2[8 * 16];

    const int tid = threadIdx.x;
    for (int idx = tid; idx < 128 * 32; idx += 256) sW1[idx] = W1[idx];
    for (int idx = tid; idx < 32 * 16; idx += 256) sW2[idx] = W2[idx];
    if (tid < 32) { sW3[tid] = W3[tid]; sB1[tid] = b1[tid]; }
    if (tid < 16) sB2[tid] = b2[tid];
    if (tid < 2) sB3[tid] = b3[tid];
    const long g0 = (long)blockIdx.x * 8;
    for (int idx = tid; idx < 1024; idx += 256) sF[idx] = feats[g0 * 128 + idx];
    __syncthreads();

    const int g = tid >> 5, h = tid & 31;
    float a1 = sB1[h];
#pragma unroll 4
    for (int k = 0; k < 128; ++k) a1 += sF[g * 128 + k] * sW1[k * 32 + h];
    sH1[g * 32 + h] = fmaxf(a1, 0.f);
    __syncthreads();

    if (h < 16) {
        float a2 = sB2[h];
#pragma unroll
        for (int k = 0; k < 32; ++k) a2 += sH1[g * 32 + k] * sW2[k * 16 + h];
        sH2[g * 16 + h] = fmaxf(a2, 0.f);
    }
    __syncthreads();

    if (h < 2) {
        float a3 = sB3[h];
#pragma unroll
        for (int k = 0; k < 16; ++k) a3 += sH2[g * 16 + k] * sW3[k * 2 + h];
        out[(g0 + g) * 2 + h] = a3;
    }
}

// ---------------------------------------------------------------------------
extern "C" void kernel_launch(void* const* d_in, const int* in_sizes, int n_in,
                              void* d_out, int out_size, void* d_ws, size_t ws_size,
                              hipStream_t stream) {
    // inputs per setup_inputs() order
    const int*   cols1 = (const int*)d_in[1];
    const float* vals1 = (const float*)d_in[2];
    const float* x1    = (const float*)d_in[3];
    const int*   cols2 = (const int*)d_in[5];
    const float* vals2 = (const float*)d_in[6];
    const float* x2    = (const float*)d_in[7];
    const float* W1a = (const float*)d_in[8];
    const float* b1a = (const float*)d_in[9];
    const float* W1b = (const float*)d_in[10];
    const float* b1b = (const float*)d_in[11];
    const float* W2a = (const float*)d_in[12];
    const float* b2a = (const float*)d_in[13];
    const float* W2b = (const float*)d_in[14];
    const float* b2b = (const float*)d_in[15];
    const float* fc1_W = (const float*)d_in[16];
    const float* fc1_b = (const float*)d_in[17];
    const float* fc2_W = (const float*)d_in[18];
    const float* fc2_b = (const float*)d_in[19];
    const float* fc3_W = (const float*)d_in[20];
    const float* fc3_b = (const float*)d_in[21];
    float* out = (float*)d_out;

    // workspace: sup (max N2*32), hbuf (max N2*32), feats (B*128)  ~53 MB
    float* sup   = (float*)d_ws;
    float* hbuf  = sup + (size_t)NN2 * 32;
    float* feats = hbuf + (size_t)NN2 * 32;

    // ---- branch 1 (116) ----
    gemm32<N1P><<<NN1 / 128, 256, 0, stream>>>(x1, W1a, sup);
    agg_relu<<<NN1 / 8, 256, 0, stream>>>(cols1, vals1, sup, b1a, hbuf);
    gemm32<HD><<<NN1 / 128, 256, 0, stream>>>(hbuf, W1b, sup);
    agg_relu<<<NN1 / 8, 256, 0, stream>>>(cols1, vals1, sup, b1b, hbuf);
    pool_meanmax<N1P><<<NB, 256, 0, stream>>>(hbuf, feats, 0);

    // ---- branch 2 (200) ----
    gemm32<N2P><<<NN2 / 128, 256, 0, stream>>>(x2, W2a, sup);
    agg_relu<<<NN2 / 8, 256, 0, stream>>>(cols2, vals2, sup, b2a, hbuf);
    gemm32<HD><<<NN2 / 128, 256, 0, stream>>>(hbuf, W2b, sup);
    agg_relu<<<NN2 / 8, 256, 0, stream>>>(cols2, vals2, sup, b2b, hbuf);
    pool_meanmax<N2P><<<NB, 256, 0, stream>>>(hbuf, feats, 64);

    // ---- MLP head ----
    mlp_head<<<NB / 8, 256, 0, stream>>>(feats, fc1_W, fc1_b, fc2_W, fc2_b,
                                         fc3_W, fc3_b, out);
}